// Round 7
// baseline (160.104 us; speedup 1.0000x reference)
//
#include <hip/hip_runtime.h>

// EdgeClassifier:
//   Hd = zd @ W1[:, :128]^T + b1   (bf16, in ws)     [N_DRUG x 128]
//   Hp = zp @ W1[:, 128:]^T        (bf16, in ws)     [N_PROT x 128]
//   out[e] = W2 . relu(Hd[row[e]] + Hp[col[e]]) + b2
// R7: XCD-aware bucketing of edges by drug-row (8 buckets), bucket b processed
// by blocks with bid%8==b so each XCD's L2 keeps a 1.6MB Hd slice resident.
// Pipeline: memset(cnt) -> hprep+hist -> scatter -> bucketed edge kernel.

typedef __attribute__((ext_vector_type(8))) short bhalf8;
typedef __attribute__((ext_vector_type(4))) float f32x4;

__device__ __forceinline__ unsigned bfr(float f) {
    unsigned u = __builtin_bit_cast(unsigned, f);
    return (u + 0x7fffu + ((u >> 16) & 1u)) >> 16;
}
__device__ __forceinline__ unsigned pk2(float a, float b) {
    return bfr(a) | (bfr(b) << 16);
}
__device__ __forceinline__ float bl(unsigned u) { return __builtin_bit_cast(float, u << 16); }
__device__ __forceinline__ float bh(unsigned u) { return __builtin_bit_cast(float, u & 0xffff0000u); }

__device__ __forceinline__ int buck(int drow, int Nd) {
    return (int)(((long long)drow * 8) / Nd);      // 0..7, consistent everywhere
}

#define NH 128          // histogram blocks appended to hprep launch
#define SCH 4096        // edges per scatter block

// ---------- K1: hprep (fused d+p) + histogram blocks ----------
__global__ __launch_bounds__(512) void hprep2h_kernel(
    const float* __restrict__ zd, const float* __restrict__ zp,
    const float* __restrict__ W1, const float* __restrict__ b1,
    unsigned short* __restrict__ Hd, unsigned short* __restrict__ Hp,
    int Nd, int Np, int nbd, int nbp,
    const int* __restrict__ eli, int E, int* __restrict__ cnt, int doHist)
{
    __shared__ __align__(16) short sZ[64 * 128];   // 16 KB, XOR-swizzled
    __shared__ int lh[8];
    const int nhp = nbd + nbp;
    const int tid = threadIdx.x;

    if ((int)blockIdx.x >= nhp) {                  // ---- histogram part ----
        if (!doHist) return;
        if (tid < 8) lh[tid] = 0;
        __syncthreads();
        const int hb = blockIdx.x - nhp;
        for (int i = hb * 512 + tid; i < E; i += NH * 512)
            atomicAdd(&lh[buck(eli[i], Nd)], 1);
        __syncthreads();
        if (tid < 8) atomicAdd(&cnt[tid], lh[tid]);
        return;
    }

    // ---- hprep part (identical to proven R4/R6 hprep2) ----
    const bool isP = (int)blockIdx.x >= nbd;
    const float* z = isP ? zp : zd;
    unsigned short* H = isP ? Hp : Hd;
    const int N    = isP ? Np : Nd;
    const int koff = isP ? 128 : 0;
    const int blk  = isP ? blockIdx.x - nbd : blockIdx.x;

    const int wave = tid >> 6;
    const int lane = tid & 63;
    const int l15  = lane & 15;
    const int lhi  = lane >> 4;
    const int ocol = wave * 16 + l15;

    bhalf8 bfrag[4];
    #pragma unroll
    for (int ks = 0; ks < 4; ++ks) {
        const float4* src = (const float4*)(W1 + ocol * 256 + koff + ks * 32 + lhi * 8);
        float4 p = src[0], q = src[1];
        bhalf8 f;
        f[0] = (short)bfr(p.x); f[1] = (short)bfr(p.y);
        f[2] = (short)bfr(p.z); f[3] = (short)bfr(p.w);
        f[4] = (short)bfr(q.x); f[5] = (short)bfr(q.y);
        f[6] = (short)bfr(q.z); f[7] = (short)bfr(q.w);
        bfrag[ks] = f;
    }
    const float bias = isP ? 0.0f : b1[ocol];
    const int r0 = blk * 64;

    {
        const int rl = tid >> 3;
        const int grow = min(r0 + rl, N - 1);
        const float4* zr = (const float4*)(z + (size_t)grow * 128);
        #pragma unroll
        for (int q = 0; q < 4; ++q) {
            const int s = (tid & 7) + q * 8;
            float4 v = zr[s];
            uint2 w; w.x = pk2(v.x, v.y); w.y = pk2(v.z, v.w);
            int byte = (rl * 256 + s * 8) ^ ((rl & 7) << 4);
            *(uint2*)((char*)sZ + byte) = w;
        }
    }
    __syncthreads();

    f32x4 acc[4] = {{0.f,0.f,0.f,0.f},{0.f,0.f,0.f,0.f},
                    {0.f,0.f,0.f,0.f},{0.f,0.f,0.f,0.f}};
    #pragma unroll
    for (int ks = 0; ks < 4; ++ks) {
        #pragma unroll
        for (int rt = 0; rt < 4; ++rt) {
            const int row = rt * 16 + l15;
            int byte = (row * 256 + ks * 64 + lhi * 16) ^ ((row & 7) << 4);
            bhalf8 af = *(const bhalf8*)((const char*)sZ + byte);
            acc[rt] = __builtin_amdgcn_mfma_f32_16x16x32_bf16(af, bfrag[ks], acc[rt], 0, 0, 0);
        }
    }
    #pragma unroll
    for (int rt = 0; rt < 4; ++rt) {
        #pragma unroll
        for (int i = 0; i < 4; ++i) {
            const int grow = r0 + rt * 16 + lhi * 4 + i;
            if (grow < N)
                H[(size_t)grow * 128 + ocol] = (unsigned short)bfr(acc[rt][i] + bias);
        }
    }
}

// ---------- K2: scatter edges into 8 drug-range buckets ----------
__global__ __launch_bounds__(256) void scatter_kernel(
    const int* __restrict__ eli, int E, int Nd,
    const int* __restrict__ cnt, int* __restrict__ cursor,
    int2* __restrict__ keys, int* __restrict__ eids)
{
    __shared__ int lh[8], lbase[8];
    const int tid = threadIdx.x;
    int pref[8];
    {
        int s = 0;
        #pragma unroll
        for (int k = 0; k < 8; ++k) { pref[k] = s; s += cnt[k]; }
    }
    const int start = blockIdx.x * SCH;
    if (start >= E) return;
    if (tid < 8) lh[tid] = 0;
    __syncthreads();

    int rowv[16], colv[16], bb[16];
    #pragma unroll
    for (int q = 0; q < 16; ++q) {
        const int i = start + q * 256 + tid;
        if (i < E) {
            rowv[q] = eli[i]; colv[q] = eli[E + i];
            bb[q] = buck(rowv[q], Nd);
            atomicAdd(&lh[bb[q]], 1);
        } else bb[q] = -1;
    }
    __syncthreads();
    if (tid < 8) { lbase[tid] = pref[tid] + atomicAdd(&cursor[tid], lh[tid]); }
    __syncthreads();
    if (tid < 8) lh[tid] = 0;
    __syncthreads();
    #pragma unroll
    for (int q = 0; q < 16; ++q) {
        if (bb[q] >= 0) {
            const int r = atomicAdd(&lh[bb[q]], 1);
            const int slot = lbase[bb[q]] + r;
            keys[slot] = make_int2(rowv[q], colv[q]);
            eids[slot] = start + q * 256 + tid;
        }
    }
}

// ---------- K3: bucketed edge pass (bucket = blockIdx % 8 -> XCD) ----------
__global__ __launch_bounds__(256, 4) void edge_b_kernel(
    const unsigned short* __restrict__ Hd, const unsigned short* __restrict__ Hp,
    const int2* __restrict__ keys, const int* __restrict__ eids,
    const int* __restrict__ cnt, const float* __restrict__ W2,
    const float* __restrict__ b2, float* __restrict__ out)
{
    const int sub = threadIdx.x & 15;
    const int grp = threadIdx.x >> 4;
    float4 w2a = ((const float4*)W2)[sub * 2];
    float4 w2b = ((const float4*)W2)[sub * 2 + 1];
    const float b2v = b2[0];

    const int b = blockIdx.x & 7;
    int startP = 0, cb = 0;
    {
        int s = 0;
        #pragma unroll
        for (int k = 0; k < 8; ++k) { int c = cnt[k]; if (k < b) s += c; if (k == b) cb = c; }
        startP = s;
    }
    const int end = startP + cb;
    const int lb = blockIdx.x >> 3, nlb = gridDim.x >> 3;
    const int EPB = 128;
    int base = startP + lb * EPB;
    if (base >= end) return;
    const int step = nlb * EPB;

    int row[8], col[8], eid[8];
    #pragma unroll
    for (int u = 0; u < 8; ++u) {
        const int i = base + grp * 8 + u;
        if (i < end) { int2 k2 = keys[i]; row[u] = k2.x; col[u] = k2.y; eid[u] = eids[i]; }
        else { row[u] = 0; col[u] = 0; eid[u] = -1; }
    }

    for (; base < end; base += step) {
        uint4 hd[8], hp[8];
        #pragma unroll
        for (int u = 0; u < 8; ++u) {
            hd[u] = ((const uint4*)(Hd + (size_t)row[u] * 128))[sub];
            hp[u] = ((const uint4*)(Hp + (size_t)col[u] * 128))[sub];
        }
        const int nbase = base + step;
        int nrow[8], ncol[8], neid[8];
        if (nbase < end) {
            #pragma unroll
            for (int u = 0; u < 8; ++u) {
                const int i = nbase + grp * 8 + u;
                if (i < end) { int2 k2 = keys[i]; nrow[u] = k2.x; ncol[u] = k2.y; neid[u] = eids[i]; }
                else { nrow[u] = 0; ncol[u] = 0; neid[u] = -1; }
            }
        }
        #pragma unroll
        for (int u = 0; u < 8; ++u) {
            float s = 0.f;
            s = fmaf(fmaxf(bl(hd[u].x) + bl(hp[u].x), 0.f), w2a.x, s);
            s = fmaf(fmaxf(bh(hd[u].x) + bh(hp[u].x), 0.f), w2a.y, s);
            s = fmaf(fmaxf(bl(hd[u].y) + bl(hp[u].y), 0.f), w2a.z, s);
            s = fmaf(fmaxf(bh(hd[u].y) + bh(hp[u].y), 0.f), w2a.w, s);
            s = fmaf(fmaxf(bl(hd[u].z) + bl(hp[u].z), 0.f), w2b.x, s);
            s = fmaf(fmaxf(bh(hd[u].z) + bh(hp[u].z), 0.f), w2b.y, s);
            s = fmaf(fmaxf(bl(hd[u].w) + bl(hp[u].w), 0.f), w2b.z, s);
            s = fmaf(fmaxf(bh(hd[u].w) + bh(hp[u].w), 0.f), w2b.w, s);
            s += __shfl_xor(s, 1, 64);
            s += __shfl_xor(s, 2, 64);
            s += __shfl_xor(s, 4, 64);
            s += __shfl_xor(s, 8, 64);
            if (sub == 0 && eid[u] >= 0) out[eid[u]] = s + b2v;
        }
        if (nbase < end) {
            #pragma unroll
            for (int u = 0; u < 8; ++u) { row[u] = nrow[u]; col[u] = ncol[u]; eid[u] = neid[u]; }
        }
    }
}

// ---------- non-bucketed edge pass (R6, fallback when ws lacks bucket space) ----------
__global__ __launch_bounds__(256, 4) void edge_kernel(
    const unsigned short* __restrict__ Hd, const unsigned short* __restrict__ Hp,
    const int* __restrict__ eli, const float* __restrict__ W2,
    const float* __restrict__ b2, float* __restrict__ out, int E)
{
    const int sub = threadIdx.x & 15;
    const int grp = threadIdx.x >> 4;
    float4 w2a = ((const float4*)W2)[sub * 2];
    float4 w2b = ((const float4*)W2)[sub * 2 + 1];
    const float b2v = b2[0];

    const int EPB = 16 * 8;
    const int step = gridDim.x * EPB;
    int base = blockIdx.x * EPB;
    if (base >= E) return;

    int row[8], col[8];
    #pragma unroll
    for (int u = 0; u < 8; ++u) {
        const int e = base + grp * 8 + u;
        row[u] = (e < E) ? eli[e] : 0;
        col[u] = (e < E) ? eli[E + e] : 0;
    }

    for (; base < E; base += step) {
        uint4 hd[8], hp[8];
        #pragma unroll
        for (int u = 0; u < 8; ++u) {
            hd[u] = ((const uint4*)(Hd + (size_t)row[u] * 128))[sub];
            hp[u] = ((const uint4*)(Hp + (size_t)col[u] * 128))[sub];
        }
        const int nb = base + step;
        if (nb < E) {
            #pragma unroll
            for (int u = 0; u < 8; ++u) {
                const int e = nb + grp * 8 + u;
                row[u] = (e < E) ? eli[e] : 0;
                col[u] = (e < E) ? eli[E + e] : 0;
            }
        }
        #pragma unroll
        for (int u = 0; u < 8; ++u) {
            float s = 0.f;
            s = fmaf(fmaxf(bl(hd[u].x) + bl(hp[u].x), 0.f), w2a.x, s);
            s = fmaf(fmaxf(bh(hd[u].x) + bh(hp[u].x), 0.f), w2a.y, s);
            s = fmaf(fmaxf(bl(hd[u].y) + bl(hp[u].y), 0.f), w2a.z, s);
            s = fmaf(fmaxf(bh(hd[u].y) + bh(hp[u].y), 0.f), w2a.w, s);
            s = fmaf(fmaxf(bl(hd[u].z) + bl(hp[u].z), 0.f), w2b.x, s);
            s = fmaf(fmaxf(bh(hd[u].z) + bh(hp[u].z), 0.f), w2b.y, s);
            s = fmaf(fmaxf(bl(hd[u].w) + bl(hp[u].w), 0.f), w2b.z, s);
            s = fmaf(fmaxf(bh(hd[u].w) + bh(hp[u].w), 0.f), w2b.w, s);
            s += __shfl_xor(s, 1, 64);
            s += __shfl_xor(s, 2, 64);
            s += __shfl_xor(s, 4, 64);
            s += __shfl_xor(s, 8, 64);
            const int e = base + grp * 8 + u;
            if (sub == 0 && e < E) out[e] = s + b2v;
        }
    }
}

// ---------- last-resort fallback: proven R1 kernel ----------
#define TE 64
__global__ __launch_bounds__(512, 4) void ec_fallback(
    const float* __restrict__ zd, const float* __restrict__ zp,
    const int* __restrict__ eli, const float* __restrict__ W1,
    const float* __restrict__ b1, const float* __restrict__ W2,
    const float* __restrict__ b2, float* __restrict__ out,
    int E, int nTiles)
{
    __shared__ __align__(16) short sZ[TE * 256];
    __shared__ float sPart[8][TE];
    const int tid  = threadIdx.x;
    const int wave = tid >> 6;
    const int lane = tid & 63;
    const int l15  = lane & 15;
    const int lhi  = lane >> 4;
    const int ocol = wave * 16 + l15;
    bhalf8 bfrag[8];
    #pragma unroll
    for (int ks = 0; ks < 8; ++ks) {
        const float4* src = (const float4*)(W1 + ocol * 256 + ks * 32 + lhi * 8);
        float4 p = src[0], q = src[1];
        bhalf8 f;
        f[0] = (short)bfr(p.x); f[1] = (short)bfr(p.y);
        f[2] = (short)bfr(p.z); f[3] = (short)bfr(p.w);
        f[4] = (short)bfr(q.x); f[5] = (short)bfr(q.y);
        f[6] = (short)bfr(q.z); f[7] = (short)bfr(q.w);
        bfrag[ks] = f;
    }
    const float b1v = b1[ocol];
    const float w2v = W2[ocol];
    const float b2v = b2[0];
    const int slot = tid >> 5;
    const int lane32 = tid & 31;
    for (int tile = blockIdx.x; tile < nTiles; tile += gridDim.x) {
        const int base = tile * TE;
        __syncthreads();
        #pragma unroll
        for (int r = 0; r < 4; ++r) {
            const int e  = slot * 4 + r;
            const int eg = base + e;
            int drow = 0, pcol = 0;
            if (eg < E) { drow = eli[eg]; pcol = eli[E + eg]; }
            float4 v = ((const float4*)(zd + (size_t)drow * 128))[lane32];
            float4 u = ((const float4*)(zp + (size_t)pcol * 128))[lane32];
            int byte0 = (e * 512 + lane32 * 8) ^ ((e & 7) << 4);
            uint2 pv; pv.x = pk2(v.x, v.y); pv.y = pk2(v.z, v.w);
            *(uint2*)((char*)sZ + byte0) = pv;
            int byte1 = (e * 512 + 256 + lane32 * 8) ^ ((e & 7) << 4);
            uint2 pu; pu.x = pk2(u.x, u.y); pu.y = pk2(u.z, u.w);
            *(uint2*)((char*)sZ + byte1) = pu;
        }
        __syncthreads();
        f32x4 acc[4] = {{0.f,0.f,0.f,0.f},{0.f,0.f,0.f,0.f},
                        {0.f,0.f,0.f,0.f},{0.f,0.f,0.f,0.f}};
        #pragma unroll
        for (int ks = 0; ks < 8; ++ks) {
            const int kb = (ks * 32 + lhi * 8) * 2;
            #pragma unroll
            for (int rt = 0; rt < 4; ++rt) {
                const int row = rt * 16 + l15;
                int byte = (row * 512 + kb) ^ ((row & 7) << 4);
                bhalf8 af = *(const bhalf8*)((const char*)sZ + byte);
                acc[rt] = __builtin_amdgcn_mfma_f32_16x16x32_bf16(af, bfrag[ks], acc[rt], 0, 0, 0);
            }
        }
        #pragma unroll
        for (int rt = 0; rt < 4; ++rt) {
            #pragma unroll
            for (int i = 0; i < 4; ++i) {
                float v = acc[rt][i] + b1v;
                v = fmaxf(v, 0.0f) * w2v;
                v += __shfl_xor(v, 1, 64);
                v += __shfl_xor(v, 2, 64);
                v += __shfl_xor(v, 4, 64);
                v += __shfl_xor(v, 8, 64);
                if (l15 == 0) sPart[wave][rt * 16 + lhi * 4 + i] = v;
            }
        }
        __syncthreads();
        if (tid < TE) {
            const int eg = base + tid;
            if (eg < E) {
                float s = b2v;
                #pragma unroll
                for (int w = 0; w < 8; ++w) s += sPart[w][tid];
                out[eg] = s;
            }
        }
    }
}

extern "C" void kernel_launch(void* const* d_in, const int* in_sizes, int n_in,
                              void* d_out, int out_size, void* d_ws, size_t ws_size,
                              hipStream_t stream) {
    const float* zd = (const float*)d_in[0];
    const float* zp = (const float*)d_in[1];
    const int*   eli = (const int*)d_in[2];
    const float* W1 = (const float*)d_in[3];
    const float* b1 = (const float*)d_in[4];
    const float* W2 = (const float*)d_in[5];
    const float* b2 = (const float*)d_in[6];
    float* out = (float*)d_out;

    const int E  = in_sizes[2] / 2;
    const int nd = in_sizes[0];        // N_DRUG * 128
    const int np = in_sizes[1];        // N_PROT * 128
    const int Nd = nd / 128, Np = np / 128;
    const int nbd = (Nd + 63) / 64, nbp = (Np + 63) / 64;

    const size_t bytesH = ((size_t)nd + (size_t)np) * sizeof(unsigned short);
    const size_t offKeys = (bytesH + 15) & ~(size_t)15;
    const size_t offEids = offKeys + (size_t)E * sizeof(int2);
    const size_t offCnt  = (offEids + (size_t)E * sizeof(int) + 63) & ~(size_t)63;
    const size_t need2 = offCnt + 128;

    if (ws_size >= need2) {
        unsigned short* Hd = (unsigned short*)d_ws;
        unsigned short* Hp = Hd + nd;
        int2* keys  = (int2*)((char*)d_ws + offKeys);
        int*  eids  = (int*)((char*)d_ws + offEids);
        int*  cnt   = (int*)((char*)d_ws + offCnt);     // cnt[8] + cursor[8]
        int*  cursor = cnt + 8;

        hipMemsetAsync(cnt, 0, 64, stream);
        hipLaunchKernelGGL(hprep2h_kernel, dim3(nbd + nbp + NH), dim3(512), 0, stream,
                           zd, zp, W1, b1, Hd, Hp, Nd, Np, nbd, nbp, eli, E, cnt, 1);
        hipLaunchKernelGGL(scatter_kernel, dim3((E + SCH - 1) / SCH), dim3(256), 0, stream,
                           eli, E, Nd, cnt, cursor, keys, eids);
        hipLaunchKernelGGL(edge_b_kernel, dim3(4096), dim3(256), 0, stream,
                           Hd, Hp, keys, eids, cnt, W2, b2, out);
    } else if (ws_size >= bytesH) {
        unsigned short* Hd = (unsigned short*)d_ws;
        unsigned short* Hp = Hd + nd;
        hipLaunchKernelGGL(hprep2h_kernel, dim3(nbd + nbp), dim3(512), 0, stream,
                           zd, zp, W1, b1, Hd, Hp, Nd, Np, nbd, nbp, eli, E, (int*)nullptr, 0);
        hipLaunchKernelGGL(edge_kernel, dim3(4096), dim3(256), 0, stream,
                           Hd, Hp, eli, W2, b2, out, E);
    } else {
        const int nTiles = (E + TE - 1) / TE;
        hipLaunchKernelGGL(ec_fallback, dim3(2048), dim3(512), 0, stream,
                           zd, zp, eli, W1, b1, W2, b2, out, E, nTiles);
    }
}

// Round 8
// 65.438 us; speedup vs baseline: 2.4466x; 2.4466x over previous
//
#include <hip/hip_runtime.h>

// EdgeClassifier:
//   Hd = q8(zd @ W1[:, :128]^T + b1), per-row scale   [N_DRUG x 128] int8
//   Hp = q8(zp @ W1[:, 128:]^T),      per-row scale   [N_PROT x 128] int8
//   out[e] = W2 . relu(Hd[row]*sd + Hp[col]*sp) + b2
// R8: int8 H tables halve gather bytes (edge pass is traffic-paced at ~3.4TB/s).
// Bucketing (R7) reverted: scattered out-writes amplified 50x, no L2 gain.

typedef __attribute__((ext_vector_type(8))) short bhalf8;
typedef __attribute__((ext_vector_type(4))) float f32x4;

__device__ __forceinline__ unsigned bfr(float f) {
    unsigned u = __builtin_bit_cast(unsigned, f);
    return (u + 0x7fffu + ((u >> 16) & 1u)) >> 16;
}
__device__ __forceinline__ unsigned pk2(float a, float b) {
    return bfr(a) | (bfr(b) << 16);
}
__device__ __forceinline__ float db(unsigned w, int b) {   // signed byte b of w -> float
    return (float)(int)(signed char)((w >> (b * 8)) & 0xffu);
}

#define SH_STRIDE 132   // fp32 elems; 528B rows: 16B-aligned, <=4-way LDS conflicts

// ---------- K1: H-prep GEMM + per-row int8 quantize ----------
// one block = 64 rows of one table; blocks [0,nbd) -> drug, rest -> protein
__global__ __launch_bounds__(512) void hprepq_kernel(
    const float* __restrict__ zd, const float* __restrict__ zp,
    const float* __restrict__ W1, const float* __restrict__ b1,
    signed char* __restrict__ Hd, signed char* __restrict__ Hp,
    float* __restrict__ scD, float* __restrict__ scP,
    int Nd, int Np, int nbd)
{
    __shared__ __align__(16) char smem[64 * SH_STRIDE * 4];   // 33.8 KB
    short* sZ = (short*)smem;          // staging view (16 KB, XOR-swizzled)
    float* sH = (float*)smem;          // h-transpose view (stride SH_STRIDE)

    const bool isP = (int)blockIdx.x >= nbd;
    const float* z = isP ? zp : zd;
    signed char* H = isP ? Hp : Hd;
    float* sc = isP ? scP : scD;
    const int N    = isP ? Np : Nd;
    const int koff = isP ? 128 : 0;
    const int blk  = isP ? blockIdx.x - nbd : blockIdx.x;

    const int tid  = threadIdx.x;
    const int wave = tid >> 6;
    const int lane = tid & 63;
    const int l15  = lane & 15;
    const int lhi  = lane >> 4;
    const int ocol = wave * 16 + l15;

    bhalf8 bfrag[4];
    #pragma unroll
    for (int ks = 0; ks < 4; ++ks) {
        const float4* src = (const float4*)(W1 + ocol * 256 + koff + ks * 32 + lhi * 8);
        float4 p = src[0], q = src[1];
        bhalf8 f;
        f[0] = (short)bfr(p.x); f[1] = (short)bfr(p.y);
        f[2] = (short)bfr(p.z); f[3] = (short)bfr(p.w);
        f[4] = (short)bfr(q.x); f[5] = (short)bfr(q.y);
        f[6] = (short)bfr(q.z); f[7] = (short)bfr(q.w);
        bfrag[ks] = f;
    }
    const float bias = isP ? 0.0f : b1[ocol];
    const int r0 = blk * 64;

    // stage 64 rows x 128 fp32 -> bf16 LDS (8 threads/row)
    {
        const int rl = tid >> 3;
        const int grow = min(r0 + rl, N - 1);
        const float4* zr = (const float4*)(z + (size_t)grow * 128);
        #pragma unroll
        for (int q = 0; q < 4; ++q) {
            const int s = (tid & 7) + q * 8;
            float4 v = zr[s];
            uint2 w; w.x = pk2(v.x, v.y); w.y = pk2(v.z, v.w);
            int byte = (rl * 256 + s * 8) ^ ((rl & 7) << 4);
            *(uint2*)((char*)sZ + byte) = w;
        }
    }
    __syncthreads();

    f32x4 acc[4] = {{0.f,0.f,0.f,0.f},{0.f,0.f,0.f,0.f},
                    {0.f,0.f,0.f,0.f},{0.f,0.f,0.f,0.f}};
    #pragma unroll
    for (int ks = 0; ks < 4; ++ks) {
        #pragma unroll
        for (int rt = 0; rt < 4; ++rt) {
            const int row = rt * 16 + l15;
            int byte = (row * 256 + ks * 64 + lhi * 16) ^ ((row & 7) << 4);
            bhalf8 af = *(const bhalf8*)((const char*)sZ + byte);
            acc[rt] = __builtin_amdgcn_mfma_f32_16x16x32_bf16(af, bfrag[ks], acc[rt], 0, 0, 0);
        }
    }
    __syncthreads();   // done reading sZ; smem becomes sH

    // transpose h into LDS: sH[row][col], row-major stride SH_STRIDE
    #pragma unroll
    for (int rt = 0; rt < 4; ++rt) {
        #pragma unroll
        for (int i = 0; i < 4; ++i) {
            const int row = rt * 16 + lhi * 4 + i;
            sH[row * SH_STRIDE + ocol] = acc[rt][i] + bias;
        }
    }
    __syncthreads();

    // per-row absmax + quantize: 8 threads/row, 16 cols each
    {
        const int qrow = tid >> 3;
        const int k    = tid & 7;
        float4 v4[4];
        float mx = 0.0f;
        #pragma unroll
        for (int j = 0; j < 4; ++j) {
            v4[j] = *(const float4*)(sH + qrow * SH_STRIDE + k * 16 + j * 4);
            mx = fmaxf(mx, fmaxf(fmaxf(fabsf(v4[j].x), fabsf(v4[j].y)),
                                 fmaxf(fabsf(v4[j].z), fabsf(v4[j].w))));
        }
        mx = fmaxf(mx, __shfl_xor(mx, 1, 64));
        mx = fmaxf(mx, __shfl_xor(mx, 2, 64));
        mx = fmaxf(mx, __shfl_xor(mx, 4, 64));
        const float inv = 127.0f / fmaxf(mx, 1e-20f);
        uint4 o;
        unsigned ob[4];
        #pragma unroll
        for (int j = 0; j < 4; ++j) {
            int a0 = __float2int_rn(v4[j].x * inv);
            int a1 = __float2int_rn(v4[j].y * inv);
            int a2 = __float2int_rn(v4[j].z * inv);
            int a3 = __float2int_rn(v4[j].w * inv);
            ob[j] = (unsigned)(a0 & 0xff) | ((unsigned)(a1 & 0xff) << 8) |
                    ((unsigned)(a2 & 0xff) << 16) | ((unsigned)(a3 & 0xff) << 24);
        }
        o.x = ob[0]; o.y = ob[1]; o.z = ob[2]; o.w = ob[3];
        const int grow = r0 + qrow;
        if (grow < N) {
            *(uint4*)(H + (size_t)grow * 128 + k * 16) = o;
            if (k == 0) sc[grow] = mx * (1.0f / 127.0f);
        }
    }
}

// ---------- K2: per-edge gather (int8) + dequant + relu + dot(W2) ----------
// 16 lanes/edge, 8 int8 elems/lane; 8 edges/group/iter; idx prefetch 1 ahead
__global__ __launch_bounds__(256, 4) void edgeq_kernel(
    const signed char* __restrict__ Hd, const signed char* __restrict__ Hp,
    const float* __restrict__ scD, const float* __restrict__ scP,
    const int* __restrict__ eli, const float* __restrict__ W2,
    const float* __restrict__ b2, float* __restrict__ out, int E)
{
    const int sub = threadIdx.x & 15;
    const int grp = threadIdx.x >> 4;
    float4 w2a = ((const float4*)W2)[sub * 2];       // coeffs for elems sub*8..+3
    float4 w2b = ((const float4*)W2)[sub * 2 + 1];   // elems sub*8+4..+7
    const float b2v = b2[0];

    const int EPB = 16 * 8;                          // 128 edges per block-iter
    const int step = gridDim.x * EPB;
    int base = blockIdx.x * EPB;
    if (base >= E) return;

    int row[8], col[8];
    #pragma unroll
    for (int u = 0; u < 8; ++u) {
        const int e = base + grp * 8 + u;
        row[u] = (e < E) ? eli[e] : 0;
        col[u] = (e < E) ? eli[E + e] : 0;
    }

    for (; base < E; base += step) {
        uint2 qd[8], qp[8];
        float sd[8], sp[8];
        #pragma unroll
        for (int u = 0; u < 8; ++u) {
            qd[u] = *(const uint2*)(Hd + (size_t)row[u] * 128 + sub * 8);
            qp[u] = *(const uint2*)(Hp + (size_t)col[u] * 128 + sub * 8);
            sd[u] = scD[row[u]];
            sp[u] = scP[col[u]];
        }
        const int nb = base + step;
        if (nb < E) {
            #pragma unroll
            for (int u = 0; u < 8; ++u) {
                const int e = nb + grp * 8 + u;
                row[u] = (e < E) ? eli[e] : 0;
                col[u] = (e < E) ? eli[E + e] : 0;
            }
        }
        #pragma unroll
        for (int u = 0; u < 8; ++u) {
            float s = 0.f;
            const unsigned dx = qd[u].x, dy = qd[u].y;
            const unsigned px = qp[u].x, py = qp[u].y;
            s = fmaf(fmaxf(db(dx,0) * sd[u] + db(px,0) * sp[u], 0.f), w2a.x, s);
            s = fmaf(fmaxf(db(dx,1) * sd[u] + db(px,1) * sp[u], 0.f), w2a.y, s);
            s = fmaf(fmaxf(db(dx,2) * sd[u] + db(px,2) * sp[u], 0.f), w2a.z, s);
            s = fmaf(fmaxf(db(dx,3) * sd[u] + db(px,3) * sp[u], 0.f), w2a.w, s);
            s = fmaf(fmaxf(db(dy,0) * sd[u] + db(py,0) * sp[u], 0.f), w2b.x, s);
            s = fmaf(fmaxf(db(dy,1) * sd[u] + db(py,1) * sp[u], 0.f), w2b.y, s);
            s = fmaf(fmaxf(db(dy,2) * sd[u] + db(py,2) * sp[u], 0.f), w2b.z, s);
            s = fmaf(fmaxf(db(dy,3) * sd[u] + db(py,3) * sp[u], 0.f), w2b.w, s);
            s += __shfl_xor(s, 1, 64);
            s += __shfl_xor(s, 2, 64);
            s += __shfl_xor(s, 4, 64);
            s += __shfl_xor(s, 8, 64);
            const int e = base + grp * 8 + u;
            if (sub == 0 && e < E) out[e] = s + b2v;   // coalesced per group
        }
    }
}

// ---------- last-resort fallback: proven R1 kernel ----------
#define TE 64
__global__ __launch_bounds__(512, 4) void ec_fallback(
    const float* __restrict__ zd, const float* __restrict__ zp,
    const int* __restrict__ eli, const float* __restrict__ W1,
    const float* __restrict__ b1, const float* __restrict__ W2,
    const float* __restrict__ b2, float* __restrict__ out,
    int E, int nTiles)
{
    __shared__ __align__(16) short sZ[TE * 256];
    __shared__ float sPart[8][TE];
    const int tid  = threadIdx.x;
    const int wave = tid >> 6;
    const int lane = tid & 63;
    const int l15  = lane & 15;
    const int lhi  = lane >> 4;
    const int ocol = wave * 16 + l15;
    bhalf8 bfrag[8];
    #pragma unroll
    for (int ks = 0; ks < 8; ++ks) {
        const float4* src = (const float4*)(W1 + ocol * 256 + ks * 32 + lhi * 8);
        float4 p = src[0], q = src[1];
        bhalf8 f;
        f[0] = (short)bfr(p.x); f[1] = (short)bfr(p.y);
        f[2] = (short)bfr(p.z); f[3] = (short)bfr(p.w);
        f[4] = (short)bfr(q.x); f[5] = (short)bfr(q.y);
        f[6] = (short)bfr(q.z); f[7] = (short)bfr(q.w);
        bfrag[ks] = f;
    }
    const float b1v = b1[ocol];
    const float w2v = W2[ocol];
    const float b2v = b2[0];
    const int slot = tid >> 5;
    const int lane32 = tid & 31;
    for (int tile = blockIdx.x; tile < nTiles; tile += gridDim.x) {
        const int base = tile * TE;
        __syncthreads();
        #pragma unroll
        for (int r = 0; r < 4; ++r) {
            const int e  = slot * 4 + r;
            const int eg = base + e;
            int drow = 0, pcol = 0;
            if (eg < E) { drow = eli[eg]; pcol = eli[E + eg]; }
            float4 v = ((const float4*)(zd + (size_t)drow * 128))[lane32];
            float4 u = ((const float4*)(zp + (size_t)pcol * 128))[lane32];
            int byte0 = (e * 512 + lane32 * 8) ^ ((e & 7) << 4);
            uint2 pv; pv.x = pk2(v.x, v.y); pv.y = pk2(v.z, v.w);
            *(uint2*)((char*)sZ + byte0) = pv;
            int byte1 = (e * 512 + 256 + lane32 * 8) ^ ((e & 7) << 4);
            uint2 pu; pu.x = pk2(u.x, u.y); pu.y = pk2(u.z, u.w);
            *(uint2*)((char*)sZ + byte1) = pu;
        }
        __syncthreads();
        f32x4 acc[4] = {{0.f,0.f,0.f,0.f},{0.f,0.f,0.f,0.f},
                        {0.f,0.f,0.f,0.f},{0.f,0.f,0.f,0.f}};
        #pragma unroll
        for (int ks = 0; ks < 8; ++ks) {
            const int kb = (ks * 32 + lhi * 8) * 2;
            #pragma unroll
            for (int rt = 0; rt < 4; ++rt) {
                const int row = rt * 16 + l15;
                int byte = (row * 512 + kb) ^ ((row & 7) << 4);
                bhalf8 af = *(const bhalf8*)((const char*)sZ + byte);
                acc[rt] = __builtin_amdgcn_mfma_f32_16x16x32_bf16(af, bfrag[ks], acc[rt], 0, 0, 0);
            }
        }
        #pragma unroll
        for (int rt = 0; rt < 4; ++rt) {
            #pragma unroll
            for (int i = 0; i < 4; ++i) {
                float v = acc[rt][i] + b1v;
                v = fmaxf(v, 0.0f) * w2v;
                v += __shfl_xor(v, 1, 64);
                v += __shfl_xor(v, 2, 64);
                v += __shfl_xor(v, 4, 64);
                v += __shfl_xor(v, 8, 64);
                if (l15 == 0) sPart[wave][rt * 16 + lhi * 4 + i] = v;
            }
        }
        __syncthreads();
        if (tid < TE) {
            const int eg = base + tid;
            if (eg < E) {
                float s = b2v;
                #pragma unroll
                for (int w = 0; w < 8; ++w) s += sPart[w][tid];
                out[eg] = s;
            }
        }
    }
}

extern "C" void kernel_launch(void* const* d_in, const int* in_sizes, int n_in,
                              void* d_out, int out_size, void* d_ws, size_t ws_size,
                              hipStream_t stream) {
    const float* zd = (const float*)d_in[0];
    const float* zp = (const float*)d_in[1];
    const int*   eli = (const int*)d_in[2];
    const float* W1 = (const float*)d_in[3];
    const float* b1 = (const float*)d_in[4];
    const float* W2 = (const float*)d_in[5];
    const float* b2 = (const float*)d_in[6];
    float* out = (float*)d_out;

    const int E  = in_sizes[2] / 2;
    const int nd = in_sizes[0];        // N_DRUG * 128
    const int np = in_sizes[1];        // N_PROT * 128
    const int Nd = nd / 128, Np = np / 128;
    const int nbd = (Nd + 63) / 64, nbp = (Np + 63) / 64;

    // ws layout: Hd int8 | Hp int8 | scD f32 | scP f32
    const size_t offHp = (size_t)Nd * 128;
    const size_t offSd = (offHp + (size_t)Np * 128 + 15) & ~(size_t)15;
    const size_t offSp = offSd + (size_t)Nd * sizeof(float);
    const size_t need  = offSp + (size_t)Np * sizeof(float);

    if (ws_size >= need) {
        signed char* Hd = (signed char*)d_ws;
        signed char* Hp = Hd + offHp;
        float* scD = (float*)((char*)d_ws + offSd);
        float* scP = (float*)((char*)d_ws + offSp);
        hipLaunchKernelGGL(hprepq_kernel, dim3(nbd + nbp), dim3(512), 0, stream,
                           zd, zp, W1, b1, Hd, Hp, scD, scP, Nd, Np, nbd);
        hipLaunchKernelGGL(edgeq_kernel, dim3(4096), dim3(256), 0, stream,
                           Hd, Hp, scD, scP, eli, W2, b2, out, E);
    } else {
        const int nTiles = (E + TE - 1) / TE;
        hipLaunchKernelGGL(ec_fallback, dim3(2048), dim3(512), 0, stream,
                           zd, zp, eli, W1, b1, W2, b2, out, E, nTiles);
    }
}

// Round 9
// 58.515 us; speedup vs baseline: 2.7361x; 1.1183x over previous
//
#include <hip/hip_runtime.h>

// EdgeClassifier:
//   Hd = q8(zd @ W1[:, :128]^T + b1), per-row scale   [N_DRUG x 128] int8
//   Hp = q8(zp @ W1[:, 128:]^T),      per-row scale   [N_PROT x 128] int8
//   out[e] = W2 . relu(Hd[row]*sd + Hp[col]*sp) + b2
// R9: edge VALU trim — relu-scale factoring (sd*relu(qd + (sp/sd)*qp)),
//     8 lanes/edge with uint4 loads (half the load instrs, 3-step reduce).

typedef __attribute__((ext_vector_type(8))) short bhalf8;
typedef __attribute__((ext_vector_type(4))) float f32x4;

__device__ __forceinline__ unsigned bfr(float f) {
    unsigned u = __builtin_bit_cast(unsigned, f);
    return (u + 0x7fffu + ((u >> 16) & 1u)) >> 16;
}
__device__ __forceinline__ unsigned pk2(float a, float b) {
    return bfr(a) | (bfr(b) << 16);
}
__device__ __forceinline__ float db(unsigned w, int b) {   // signed byte b of w -> float
    return (float)(int)(signed char)((w >> (b * 8)) & 0xffu);
}

#define SH_STRIDE 132   // fp32 elems; 528B rows: 16B-aligned, <=4-way LDS conflicts

// ---------- K1: H-prep GEMM + per-row int8 quantize (unchanged from R8) ----------
__global__ __launch_bounds__(512) void hprepq_kernel(
    const float* __restrict__ zd, const float* __restrict__ zp,
    const float* __restrict__ W1, const float* __restrict__ b1,
    signed char* __restrict__ Hd, signed char* __restrict__ Hp,
    float* __restrict__ scD, float* __restrict__ scP,
    int Nd, int Np, int nbd)
{
    __shared__ __align__(16) char smem[64 * SH_STRIDE * 4];   // 33.8 KB
    short* sZ = (short*)smem;          // staging view (16 KB, XOR-swizzled)
    float* sH = (float*)smem;          // h-transpose view (stride SH_STRIDE)

    const bool isP = (int)blockIdx.x >= nbd;
    const float* z = isP ? zp : zd;
    signed char* H = isP ? Hp : Hd;
    float* sc = isP ? scP : scD;
    const int N    = isP ? Np : Nd;
    const int koff = isP ? 128 : 0;
    const int blk  = isP ? blockIdx.x - nbd : blockIdx.x;

    const int tid  = threadIdx.x;
    const int wave = tid >> 6;
    const int lane = tid & 63;
    const int l15  = lane & 15;
    const int lhi  = lane >> 4;
    const int ocol = wave * 16 + l15;

    bhalf8 bfrag[4];
    #pragma unroll
    for (int ks = 0; ks < 4; ++ks) {
        const float4* src = (const float4*)(W1 + ocol * 256 + koff + ks * 32 + lhi * 8);
        float4 p = src[0], q = src[1];
        bhalf8 f;
        f[0] = (short)bfr(p.x); f[1] = (short)bfr(p.y);
        f[2] = (short)bfr(p.z); f[3] = (short)bfr(p.w);
        f[4] = (short)bfr(q.x); f[5] = (short)bfr(q.y);
        f[6] = (short)bfr(q.z); f[7] = (short)bfr(q.w);
        bfrag[ks] = f;
    }
    const float bias = isP ? 0.0f : b1[ocol];
    const int r0 = blk * 64;

    {
        const int rl = tid >> 3;
        const int grow = min(r0 + rl, N - 1);
        const float4* zr = (const float4*)(z + (size_t)grow * 128);
        #pragma unroll
        for (int q = 0; q < 4; ++q) {
            const int s = (tid & 7) + q * 8;
            float4 v = zr[s];
            uint2 w; w.x = pk2(v.x, v.y); w.y = pk2(v.z, v.w);
            int byte = (rl * 256 + s * 8) ^ ((rl & 7) << 4);
            *(uint2*)((char*)sZ + byte) = w;
        }
    }
    __syncthreads();

    f32x4 acc[4] = {{0.f,0.f,0.f,0.f},{0.f,0.f,0.f,0.f},
                    {0.f,0.f,0.f,0.f},{0.f,0.f,0.f,0.f}};
    #pragma unroll
    for (int ks = 0; ks < 4; ++ks) {
        #pragma unroll
        for (int rt = 0; rt < 4; ++rt) {
            const int row = rt * 16 + l15;
            int byte = (row * 256 + ks * 64 + lhi * 16) ^ ((row & 7) << 4);
            bhalf8 af = *(const bhalf8*)((const char*)sZ + byte);
            acc[rt] = __builtin_amdgcn_mfma_f32_16x16x32_bf16(af, bfrag[ks], acc[rt], 0, 0, 0);
        }
    }
    __syncthreads();   // done reading sZ; smem becomes sH

    #pragma unroll
    for (int rt = 0; rt < 4; ++rt) {
        #pragma unroll
        for (int i = 0; i < 4; ++i) {
            const int row = rt * 16 + lhi * 4 + i;
            sH[row * SH_STRIDE + ocol] = acc[rt][i] + bias;
        }
    }
    __syncthreads();

    {
        const int qrow = tid >> 3;
        const int k    = tid & 7;
        float4 v4[4];
        float mx = 0.0f;
        #pragma unroll
        for (int j = 0; j < 4; ++j) {
            v4[j] = *(const float4*)(sH + qrow * SH_STRIDE + k * 16 + j * 4);
            mx = fmaxf(mx, fmaxf(fmaxf(fabsf(v4[j].x), fabsf(v4[j].y)),
                                 fmaxf(fabsf(v4[j].z), fabsf(v4[j].w))));
        }
        mx = fmaxf(mx, __shfl_xor(mx, 1, 64));
        mx = fmaxf(mx, __shfl_xor(mx, 2, 64));
        mx = fmaxf(mx, __shfl_xor(mx, 4, 64));
        const float inv = 127.0f / fmaxf(mx, 1e-20f);
        uint4 o;
        unsigned ob[4];
        #pragma unroll
        for (int j = 0; j < 4; ++j) {
            int a0 = __float2int_rn(v4[j].x * inv);
            int a1 = __float2int_rn(v4[j].y * inv);
            int a2 = __float2int_rn(v4[j].z * inv);
            int a3 = __float2int_rn(v4[j].w * inv);
            ob[j] = (unsigned)(a0 & 0xff) | ((unsigned)(a1 & 0xff) << 8) |
                    ((unsigned)(a2 & 0xff) << 16) | ((unsigned)(a3 & 0xff) << 24);
        }
        o.x = ob[0]; o.y = ob[1]; o.z = ob[2]; o.w = ob[3];
        const int grow = r0 + qrow;
        if (grow < N) {
            *(uint4*)(H + (size_t)grow * 128 + k * 16) = o;
            if (k == 0) sc[grow] = mx * (1.0f / 127.0f);
        }
    }
}

// ---------- K2: per-edge gather (int8) + factored dequant + relu + dot(W2) ----------
// 8 lanes/edge, uint4 (16 int8) per lane; 4 edges/group/iter; idx prefetch 1 ahead
__global__ __launch_bounds__(256, 4) void edgeq_kernel(
    const signed char* __restrict__ Hd, const signed char* __restrict__ Hp,
    const float* __restrict__ scD, const float* __restrict__ scP,
    const int* __restrict__ eli, const float* __restrict__ W2,
    const float* __restrict__ b2, float* __restrict__ out, int E)
{
    const int sub = threadIdx.x & 7;
    const int grp = threadIdx.x >> 3;                // 0..31
    float4 w2[4];
    #pragma unroll
    for (int j = 0; j < 4; ++j) w2[j] = ((const float4*)W2)[sub * 4 + j];
    const float b2v = b2[0];

    const int EPB = 32 * 4;                          // 128 edges per block-iter
    const int step = gridDim.x * EPB;
    int base = blockIdx.x * EPB;
    if (base >= E) return;

    int row[4], col[4];
    #pragma unroll
    for (int u = 0; u < 4; ++u) {
        const int e = base + grp * 4 + u;
        row[u] = (e < E) ? eli[e] : 0;
        col[u] = (e < E) ? eli[E + e] : 0;
    }

    for (; base < E; base += step) {
        uint4 qd[4], qp[4];
        float sdc[4], r[4];
        #pragma unroll
        for (int u = 0; u < 4; ++u) {
            qd[u] = *(const uint4*)(Hd + (size_t)row[u] * 128 + sub * 16);
            qp[u] = *(const uint4*)(Hp + (size_t)col[u] * 128 + sub * 16);
            const float sd = scD[row[u]];
            const float sp = scP[col[u]];
            sdc[u] = fmaxf(sd, 1e-25f);
            r[u]   = sp * __builtin_amdgcn_rcpf(sdc[u]);
        }
        const int nb = base + step;
        if (nb < E) {
            #pragma unroll
            for (int u = 0; u < 4; ++u) {
                const int e = nb + grp * 4 + u;
                row[u] = (e < E) ? eli[e] : 0;
                col[u] = (e < E) ? eli[E + e] : 0;
            }
        }
        #pragma unroll
        for (int u = 0; u < 4; ++u) {
            const float ru = r[u];
            float s = 0.f;
            const unsigned dws[4] = {qd[u].x, qd[u].y, qd[u].z, qd[u].w};
            const unsigned pws[4] = {qp[u].x, qp[u].y, qp[u].z, qp[u].w};
            #pragma unroll
            for (int j = 0; j < 4; ++j) {
                const unsigned d = dws[j], p = pws[j];
                s = fmaf(fmaxf(fmaf(ru, db(p,0), db(d,0)), 0.f), w2[j].x, s);
                s = fmaf(fmaxf(fmaf(ru, db(p,1), db(d,1)), 0.f), w2[j].y, s);
                s = fmaf(fmaxf(fmaf(ru, db(p,2), db(d,2)), 0.f), w2[j].z, s);
                s = fmaf(fmaxf(fmaf(ru, db(p,3), db(d,3)), 0.f), w2[j].w, s);
            }
            s += __shfl_xor(s, 1, 64);
            s += __shfl_xor(s, 2, 64);
            s += __shfl_xor(s, 4, 64);
            const int e = base + grp * 4 + u;
            if (sub == 0 && e < E) out[e] = fmaf(s, sdc[u], b2v);
        }
    }
}

// ---------- last-resort fallback: proven R1 kernel ----------
#define TE 64
__global__ __launch_bounds__(512, 4) void ec_fallback(
    const float* __restrict__ zd, const float* __restrict__ zp,
    const int* __restrict__ eli, const float* __restrict__ W1,
    const float* __restrict__ b1, const float* __restrict__ W2,
    const float* __restrict__ b2, float* __restrict__ out,
    int E, int nTiles)
{
    __shared__ __align__(16) short sZ[TE * 256];
    __shared__ float sPart[8][TE];
    const int tid  = threadIdx.x;
    const int wave = tid >> 6;
    const int lane = tid & 63;
    const int l15  = lane & 15;
    const int lhi  = lane >> 4;
    const int ocol = wave * 16 + l15;
    bhalf8 bfrag[8];
    #pragma unroll
    for (int ks = 0; ks < 8; ++ks) {
        const float4* src = (const float4*)(W1 + ocol * 256 + ks * 32 + lhi * 8);
        float4 p = src[0], q = src[1];
        bhalf8 f;
        f[0] = (short)bfr(p.x); f[1] = (short)bfr(p.y);
        f[2] = (short)bfr(p.z); f[3] = (short)bfr(p.w);
        f[4] = (short)bfr(q.x); f[5] = (short)bfr(q.y);
        f[6] = (short)bfr(q.z); f[7] = (short)bfr(q.w);
        bfrag[ks] = f;
    }
    const float b1v = b1[ocol];
    const float w2v = W2[ocol];
    const float b2v = b2[0];
    const int slot = tid >> 5;
    const int lane32 = tid & 31;
    for (int tile = blockIdx.x; tile < nTiles; tile += gridDim.x) {
        const int base = tile * TE;
        __syncthreads();
        #pragma unroll
        for (int r = 0; r < 4; ++r) {
            const int e  = slot * 4 + r;
            const int eg = base + e;
            int drow = 0, pcol = 0;
            if (eg < E) { drow = eli[eg]; pcol = eli[E + eg]; }
            float4 v = ((const float4*)(zd + (size_t)drow * 128))[lane32];
            float4 u = ((const float4*)(zp + (size_t)pcol * 128))[lane32];
            int byte0 = (e * 512 + lane32 * 8) ^ ((e & 7) << 4);
            uint2 pv; pv.x = pk2(v.x, v.y); pv.y = pk2(v.z, v.w);
            *(uint2*)((char*)sZ + byte0) = pv;
            int byte1 = (e * 512 + 256 + lane32 * 8) ^ ((e & 7) << 4);
            uint2 pu; pu.x = pk2(u.x, u.y); pu.y = pk2(u.z, u.w);
            *(uint2*)((char*)sZ + byte1) = pu;
        }
        __syncthreads();
        f32x4 acc[4] = {{0.f,0.f,0.f,0.f},{0.f,0.f,0.f,0.f},
                        {0.f,0.f,0.f,0.f},{0.f,0.f,0.f,0.f}};
        #pragma unroll
        for (int ks = 0; ks < 8; ++ks) {
            const int kb = (ks * 32 + lhi * 8) * 2;
            #pragma unroll
            for (int rt = 0; rt < 4; ++rt) {
                const int row = rt * 16 + l15;
                int byte = (row * 512 + kb) ^ ((row & 7) << 4);
                bhalf8 af = *(const bhalf8*)((const char*)sZ + byte);
                acc[rt] = __builtin_amdgcn_mfma_f32_16x16x32_bf16(af, bfrag[ks], acc[rt], 0, 0, 0);
            }
        }
        #pragma unroll
        for (int rt = 0; rt < 4; ++rt) {
            #pragma unroll
            for (int i = 0; i < 4; ++i) {
                float v = acc[rt][i] + b1v;
                v = fmaxf(v, 0.0f) * w2v;
                v += __shfl_xor(v, 1, 64);
                v += __shfl_xor(v, 2, 64);
                v += __shfl_xor(v, 4, 64);
                v += __shfl_xor(v, 8, 64);
                if (l15 == 0) sPart[wave][rt * 16 + lhi * 4 + i] = v;
            }
        }
        __syncthreads();
        if (tid < TE) {
            const int eg = base + tid;
            if (eg < E) {
                float s = b2v;
                #pragma unroll
                for (int w = 0; w < 8; ++w) s += sPart[w][tid];
                out[eg] = s;
            }
        }
    }
}

extern "C" void kernel_launch(void* const* d_in, const int* in_sizes, int n_in,
                              void* d_out, int out_size, void* d_ws, size_t ws_size,
                              hipStream_t stream) {
    const float* zd = (const float*)d_in[0];
    const float* zp = (const float*)d_in[1];
    const int*   eli = (const int*)d_in[2];
    const float* W1 = (const float*)d_in[3];
    const float* b1 = (const float*)d_in[4];
    const float* W2 = (const float*)d_in[5];
    const float* b2 = (const float*)d_in[6];
    float* out = (float*)d_out;

    const int E  = in_sizes[2] / 2;
    const int nd = in_sizes[0];        // N_DRUG * 128
    const int np = in_sizes[1];        // N_PROT * 128
    const int Nd = nd / 128, Np = np / 128;
    const int nbd = (Nd + 63) / 64, nbp = (Np + 63) / 64;

    // ws layout: Hd int8 | Hp int8 | scD f32 | scP f32
    const size_t offHp = (size_t)Nd * 128;
    const size_t offSd = (offHp + (size_t)Np * 128 + 15) & ~(size_t)15;
    const size_t offSp = offSd + (size_t)Nd * sizeof(float);
    const size_t need  = offSp + (size_t)Np * sizeof(float);

    if (ws_size >= need) {
        signed char* Hd = (signed char*)d_ws;
        signed char* Hp = Hd + offHp;
        float* scD = (float*)((char*)d_ws + offSd);
        float* scP = (float*)((char*)d_ws + offSp);
        hipLaunchKernelGGL(hprepq_kernel, dim3(nbd + nbp), dim3(512), 0, stream,
                           zd, zp, W1, b1, Hd, Hp, scD, scP, Nd, Np, nbd);
        hipLaunchKernelGGL(edgeq_kernel, dim3(4096), dim3(256), 0, stream,
                           Hd, Hp, scD, scP, eli, W2, b2, out, E);
    } else {
        const int nTiles = (E + TE - 1) / TE;
        hipLaunchKernelGGL(ec_fallback, dim3(2048), dim3(512), 0, stream,
                           zd, zp, eli, W1, b1, W2, b2, out, E, nTiles);
    }
}

// Round 10
// 57.862 us; speedup vs baseline: 2.7670x; 1.0113x over previous
//
#include <hip/hip_runtime.h>

// EdgeClassifier:
//   Hd = q8(zd @ W1[:, :128]^T + b1), per-row scale, stored BIASED (int8 xor 0x80)
//   Hp = q8(zp @ W1[:, 128:]^T),      per-row scale, biased
//   out[e] = W2 . relu(Hd[row]*sd + Hp[col]*sp) + b2
// R10: edge dequant in packed f16 — v_perm byte->f16-pair (0x64 magic), pk_sub,
//      pk_fma, pk_max, v_dot2_f32_f16. 7 -> 3.5 VALU ops/elem.

typedef __attribute__((ext_vector_type(8))) short bhalf8;
typedef __attribute__((ext_vector_type(4))) float f32x4;
typedef _Float16 half2_t __attribute__((ext_vector_type(2)));

__device__ __forceinline__ unsigned bfr(float f) {
    unsigned u = __builtin_bit_cast(unsigned, f);
    return (u + 0x7fffu + ((u >> 16) & 1u)) >> 16;
}
__device__ __forceinline__ unsigned pk2(float a, float b) {
    return bfr(a) | (bfr(b) << 16);
}

#define SH_STRIDE 132   // fp32 elems; 528B rows: 16B-aligned, <=4-way LDS conflicts

// ---------- K1: H-prep GEMM + per-row quantize to biased uint8 ----------
__global__ __launch_bounds__(512) void hprepq_kernel(
    const float* __restrict__ zd, const float* __restrict__ zp,
    const float* __restrict__ W1, const float* __restrict__ b1,
    unsigned char* __restrict__ Hd, unsigned char* __restrict__ Hp,
    float* __restrict__ scD, float* __restrict__ scP,
    int Nd, int Np, int nbd)
{
    __shared__ __align__(16) char smem[64 * SH_STRIDE * 4];   // 33.8 KB
    short* sZ = (short*)smem;          // staging view (16 KB, XOR-swizzled)
    float* sH = (float*)smem;          // h-transpose view (stride SH_STRIDE)

    const bool isP = (int)blockIdx.x >= nbd;
    const float* z = isP ? zp : zd;
    unsigned char* H = isP ? Hp : Hd;
    float* sc = isP ? scP : scD;
    const int N    = isP ? Np : Nd;
    const int koff = isP ? 128 : 0;
    const int blk  = isP ? blockIdx.x - nbd : blockIdx.x;

    const int tid  = threadIdx.x;
    const int wave = tid >> 6;
    const int lane = tid & 63;
    const int l15  = lane & 15;
    const int lhi  = lane >> 4;
    const int ocol = wave * 16 + l15;

    bhalf8 bfrag[4];
    #pragma unroll
    for (int ks = 0; ks < 4; ++ks) {
        const float4* src = (const float4*)(W1 + ocol * 256 + koff + ks * 32 + lhi * 8);
        float4 p = src[0], q = src[1];
        bhalf8 f;
        f[0] = (short)bfr(p.x); f[1] = (short)bfr(p.y);
        f[2] = (short)bfr(p.z); f[3] = (short)bfr(p.w);
        f[4] = (short)bfr(q.x); f[5] = (short)bfr(q.y);
        f[6] = (short)bfr(q.z); f[7] = (short)bfr(q.w);
        bfrag[ks] = f;
    }
    const float bias = isP ? 0.0f : b1[ocol];
    const int r0 = blk * 64;

    {
        const int rl = tid >> 3;
        const int grow = min(r0 + rl, N - 1);
        const float4* zr = (const float4*)(z + (size_t)grow * 128);
        #pragma unroll
        for (int q = 0; q < 4; ++q) {
            const int s = (tid & 7) + q * 8;
            float4 v = zr[s];
            uint2 w; w.x = pk2(v.x, v.y); w.y = pk2(v.z, v.w);
            int byte = (rl * 256 + s * 8) ^ ((rl & 7) << 4);
            *(uint2*)((char*)sZ + byte) = w;
        }
    }
    __syncthreads();

    f32x4 acc[4] = {{0.f,0.f,0.f,0.f},{0.f,0.f,0.f,0.f},
                    {0.f,0.f,0.f,0.f},{0.f,0.f,0.f,0.f}};
    #pragma unroll
    for (int ks = 0; ks < 4; ++ks) {
        #pragma unroll
        for (int rt = 0; rt < 4; ++rt) {
            const int row = rt * 16 + l15;
            int byte = (row * 256 + ks * 64 + lhi * 16) ^ ((row & 7) << 4);
            bhalf8 af = *(const bhalf8*)((const char*)sZ + byte);
            acc[rt] = __builtin_amdgcn_mfma_f32_16x16x32_bf16(af, bfrag[ks], acc[rt], 0, 0, 0);
        }
    }
    __syncthreads();   // done reading sZ; smem becomes sH

    #pragma unroll
    for (int rt = 0; rt < 4; ++rt) {
        #pragma unroll
        for (int i = 0; i < 4; ++i) {
            const int row = rt * 16 + lhi * 4 + i;
            sH[row * SH_STRIDE + ocol] = acc[rt][i] + bias;
        }
    }
    __syncthreads();

    {
        const int qrow = tid >> 3;
        const int k    = tid & 7;
        float4 v4[4];
        float mx = 0.0f;
        #pragma unroll
        for (int j = 0; j < 4; ++j) {
            v4[j] = *(const float4*)(sH + qrow * SH_STRIDE + k * 16 + j * 4);
            mx = fmaxf(mx, fmaxf(fmaxf(fabsf(v4[j].x), fabsf(v4[j].y)),
                                 fmaxf(fabsf(v4[j].z), fabsf(v4[j].w))));
        }
        mx = fmaxf(mx, __shfl_xor(mx, 1, 64));
        mx = fmaxf(mx, __shfl_xor(mx, 2, 64));
        mx = fmaxf(mx, __shfl_xor(mx, 4, 64));
        const float inv = 127.0f / fmaxf(mx, 1e-20f);
        uint4 o;
        unsigned ob[4];
        #pragma unroll
        for (int j = 0; j < 4; ++j) {
            int a0 = __float2int_rn(v4[j].x * inv);
            int a1 = __float2int_rn(v4[j].y * inv);
            int a2 = __float2int_rn(v4[j].z * inv);
            int a3 = __float2int_rn(v4[j].w * inv);
            ob[j] = ((unsigned)(a0 & 0xff) | ((unsigned)(a1 & 0xff) << 8) |
                     ((unsigned)(a2 & 0xff) << 16) | ((unsigned)(a3 & 0xff) << 24))
                    ^ 0x80808080u;                     // bias to uint8
        }
        o.x = ob[0]; o.y = ob[1]; o.z = ob[2]; o.w = ob[3];
        const int grow = r0 + qrow;
        if (grow < N) {
            *(uint4*)(H + (size_t)grow * 128 + k * 16) = o;
            if (k == 0) sc[grow] = mx * (1.0f / 127.0f);
        }
    }
}

// ---------- K2: per-edge gather + packed-f16 dequant/relu/dot ----------
// 8 lanes/edge, uint4 (16 bytes) per lane per table; 4 edges/group/iter
__global__ __launch_bounds__(256, 4) void edgeq_kernel(
    const unsigned char* __restrict__ Hd, const unsigned char* __restrict__ Hp,
    const float* __restrict__ scD, const float* __restrict__ scP,
    const int* __restrict__ eli, const float* __restrict__ W2,
    const float* __restrict__ b2, float* __restrict__ out, int E)
{
    const int sub = threadIdx.x & 7;
    const int grp = threadIdx.x >> 3;                // 0..31
    // W2 slice for elems sub*16 .. sub*16+15, as 8 f16 pairs
    half2_t w2h[8];
    #pragma unroll
    for (int j = 0; j < 8; ++j) {
        float2 w = ((const float2*)W2)[sub * 8 + j];
        w2h[j][0] = (_Float16)w.x; w2h[j][1] = (_Float16)w.y;
    }
    const float b2v = b2[0];
    const half2_t c1152 = { (_Float16)1152.0f, (_Float16)1152.0f };

    const int EPB = 32 * 4;                          // 128 edges per block-iter
    const int step = gridDim.x * EPB;
    int base = blockIdx.x * EPB;
    if (base >= E) return;

    int row[4], col[4];
    #pragma unroll
    for (int u = 0; u < 4; ++u) {
        const int e = base + grp * 4 + u;
        row[u] = (e < E) ? eli[e] : 0;
        col[u] = (e < E) ? eli[E + e] : 0;
    }

    for (; base < E; base += step) {
        uint4 qd[4], qp[4];
        float sdc[4], r[4];
        #pragma unroll
        for (int u = 0; u < 4; ++u) {
            qd[u] = *(const uint4*)(Hd + (size_t)row[u] * 128 + sub * 16);
            qp[u] = *(const uint4*)(Hp + (size_t)col[u] * 128 + sub * 16);
            const float sd = scD[row[u]];
            const float sp = scP[col[u]];
            sdc[u] = fmaxf(sd, 1e-25f);
            r[u]   = sp * __builtin_amdgcn_rcpf(sdc[u]);
        }
        const int nb = base + step;
        if (nb < E) {
            #pragma unroll
            for (int u = 0; u < 4; ++u) {
                const int e = nb + grp * 4 + u;
                row[u] = (e < E) ? eli[e] : 0;
                col[u] = (e < E) ? eli[E + e] : 0;
            }
        }
        #pragma unroll
        for (int u = 0; u < 4; ++u) {
            const _Float16 rh = (_Float16)r[u];
            const half2_t ru2 = { rh, rh };
            float s = 0.f;
            const unsigned dws[4] = {qd[u].x, qd[u].y, qd[u].z, qd[u].w};
            const unsigned pws[4] = {qp[u].x, qp[u].y, qp[u].z, qp[u].w};
            #pragma unroll
            for (int j = 0; j < 4; ++j) {
                const unsigned dw = dws[j], pw = pws[j];
                // lo pair: bytes 0,1 ; hi pair: bytes 2,3 -> f16 (1024+b)
                half2_t d0 = __builtin_bit_cast(half2_t,
                    __builtin_amdgcn_perm(0x64646464u, dw, 0x04010400u)) - c1152;
                half2_t d1 = __builtin_bit_cast(half2_t,
                    __builtin_amdgcn_perm(0x64646464u, dw, 0x04030402u)) - c1152;
                half2_t p0 = __builtin_bit_cast(half2_t,
                    __builtin_amdgcn_perm(0x64646464u, pw, 0x04010400u)) - c1152;
                half2_t p1 = __builtin_bit_cast(half2_t,
                    __builtin_amdgcn_perm(0x64646464u, pw, 0x04030402u)) - c1152;
                half2_t t0 = __builtin_elementwise_max(
                    __builtin_elementwise_fma(ru2, p0, d0), (half2_t){0, 0});
                half2_t t1 = __builtin_elementwise_max(
                    __builtin_elementwise_fma(ru2, p1, d1), (half2_t){0, 0});
                s = __builtin_amdgcn_fdot2(t0, w2h[j * 2],     s, false);
                s = __builtin_amdgcn_fdot2(t1, w2h[j * 2 + 1], s, false);
            }
            s += __shfl_xor(s, 1, 64);
            s += __shfl_xor(s, 2, 64);
            s += __shfl_xor(s, 4, 64);
            const int e = base + grp * 4 + u;
            if (sub == 0 && e < E) out[e] = fmaf(s, sdc[u], b2v);
        }
    }
}

// ---------- last-resort fallback: proven R1 kernel ----------
#define TE 64
__global__ __launch_bounds__(512, 4) void ec_fallback(
    const float* __restrict__ zd, const float* __restrict__ zp,
    const int* __restrict__ eli, const float* __restrict__ W1,
    const float* __restrict__ b1, const float* __restrict__ W2,
    const float* __restrict__ b2, float* __restrict__ out,
    int E, int nTiles)
{
    __shared__ __align__(16) short sZ[TE * 256];
    __shared__ float sPart[8][TE];
    const int tid  = threadIdx.x;
    const int wave = tid >> 6;
    const int lane = tid & 63;
    const int l15  = lane & 15;
    const int lhi  = lane >> 4;
    const int ocol = wave * 16 + l15;
    bhalf8 bfrag[8];
    #pragma unroll
    for (int ks = 0; ks < 8; ++ks) {
        const float4* src = (const float4*)(W1 + ocol * 256 + ks * 32 + lhi * 8);
        float4 p = src[0], q = src[1];
        bhalf8 f;
        f[0] = (short)bfr(p.x); f[1] = (short)bfr(p.y);
        f[2] = (short)bfr(p.z); f[3] = (short)bfr(p.w);
        f[4] = (short)bfr(q.x); f[5] = (short)bfr(q.y);
        f[6] = (short)bfr(q.z); f[7] = (short)bfr(q.w);
        bfrag[ks] = f;
    }
    const float b1v = b1[ocol];
    const float w2v = W2[ocol];
    const float b2v = b2[0];
    const int slot = tid >> 5;
    const int lane32 = tid & 31;
    for (int tile = blockIdx.x; tile < nTiles; tile += gridDim.x) {
        const int base = tile * TE;
        __syncthreads();
        #pragma unroll
        for (int r = 0; r < 4; ++r) {
            const int e  = slot * 4 + r;
            const int eg = base + e;
            int drow = 0, pcol = 0;
            if (eg < E) { drow = eli[eg]; pcol = eli[E + eg]; }
            float4 v = ((const float4*)(zd + (size_t)drow * 128))[lane32];
            float4 u = ((const float4*)(zp + (size_t)pcol * 128))[lane32];
            int byte0 = (e * 512 + lane32 * 8) ^ ((e & 7) << 4);
            uint2 pv; pv.x = pk2(v.x, v.y); pv.y = pk2(v.z, v.w);
            *(uint2*)((char*)sZ + byte0) = pv;
            int byte1 = (e * 512 + 256 + lane32 * 8) ^ ((e & 7) << 4);
            uint2 pu; pu.x = pk2(u.x, u.y); pu.y = pk2(u.z, u.w);
            *(uint2*)((char*)sZ + byte1) = pu;
        }
        __syncthreads();
        f32x4 acc[4] = {{0.f,0.f,0.f,0.f},{0.f,0.f,0.f,0.f},
                        {0.f,0.f,0.f,0.f},{0.f,0.f,0.f,0.f}};
        #pragma unroll
        for (int ks = 0; ks < 8; ++ks) {
            const int kb = (ks * 32 + lhi * 8) * 2;
            #pragma unroll
            for (int rt = 0; rt < 4; ++rt) {
                const int row = rt * 16 + l15;
                int byte = (row * 512 + kb) ^ ((row & 7) << 4);
                bhalf8 af = *(const bhalf8*)((const char*)sZ + byte);
                acc[rt] = __builtin_amdgcn_mfma_f32_16x16x32_bf16(af, bfrag[ks], acc[rt], 0, 0, 0);
            }
        }
        #pragma unroll
        for (int rt = 0; rt < 4; ++rt) {
            #pragma unroll
            for (int i = 0; i < 4; ++i) {
                float v = acc[rt][i] + b1v;
                v = fmaxf(v, 0.0f) * w2v;
                v += __shfl_xor(v, 1, 64);
                v += __shfl_xor(v, 2, 64);
                v += __shfl_xor(v, 4, 64);
                v += __shfl_xor(v, 8, 64);
                if (l15 == 0) sPart[wave][rt * 16 + lhi * 4 + i] = v;
            }
        }
        __syncthreads();
        if (tid < TE) {
            const int eg = base + tid;
            if (eg < E) {
                float s = b2v;
                #pragma unroll
                for (int w = 0; w < 8; ++w) s += sPart[w][tid];
                out[eg] = s;
            }
        }
    }
}

extern "C" void kernel_launch(void* const* d_in, const int* in_sizes, int n_in,
                              void* d_out, int out_size, void* d_ws, size_t ws_size,
                              hipStream_t stream) {
    const float* zd = (const float*)d_in[0];
    const float* zp = (const float*)d_in[1];
    const int*   eli = (const int*)d_in[2];
    const float* W1 = (const float*)d_in[3];
    const float* b1 = (const float*)d_in[4];
    const float* W2 = (const float*)d_in[5];
    const float* b2 = (const float*)d_in[6];
    float* out = (float*)d_out;

    const int E  = in_sizes[2] / 2;
    const int nd = in_sizes[0];        // N_DRUG * 128
    const int np = in_sizes[1];        // N_PROT * 128
    const int Nd = nd / 128, Np = np / 128;
    const int nbd = (Nd + 63) / 64, nbp = (Np + 63) / 64;

    // ws layout: Hd u8 | Hp u8 | scD f32 | scP f32
    const size_t offHp = (size_t)Nd * 128;
    const size_t offSd = (offHp + (size_t)Np * 128 + 15) & ~(size_t)15;
    const size_t offSp = offSd + (size_t)Nd * sizeof(float);
    const size_t need  = offSp + (size_t)Np * sizeof(float);

    if (ws_size >= need) {
        unsigned char* Hd = (unsigned char*)d_ws;
        unsigned char* Hp = Hd + offHp;
        float* scD = (float*)((char*)d_ws + offSd);
        float* scP = (float*)((char*)d_ws + offSp);
        hipLaunchKernelGGL(hprepq_kernel, dim3(nbd + nbp), dim3(512), 0, stream,
                           zd, zp, W1, b1, Hd, Hp, scD, scP, Nd, Np, nbd);
        hipLaunchKernelGGL(edgeq_kernel, dim3(4096), dim3(256), 0, stream,
                           Hd, Hp, scD, scP, eli, W2, b2, out, E);
    } else {
        const int nTiles = (E + TE - 1) / TE;
        hipLaunchKernelGGL(ec_fallback, dim3(2048), dim3(512), 0, stream,
                           zd, zp, eli, W1, b1, W2, b2, out, E, nTiles);
    }
}